// Round 1
// 377.256 us; speedup vs baseline: 1.2714x; 1.2714x over previous
//
#include <hip/hip_runtime.h>

#define NB 262144
#define HH 128
#define WW 16
#define LL 64

typedef __attribute__((ext_vector_type(8))) short bf16x8;
typedef __attribute__((ext_vector_type(4))) float f32x4;
typedef __attribute__((ext_vector_type(2))) unsigned int u32x2;

union FragU { bf16x8 v; unsigned int u[4]; };

// hardware RNE pack of two f32 -> 2x bf16 (lo = a, hi = b); bit-exact vs the
// previous bit-trick pk_bf16 for finite values
__device__ __forceinline__ unsigned int cvt_pk(float a, float b) {
    unsigned int r;
    asm("v_cvt_pk_bf16_f32 %0, %1, %2" : "=v"(r) : "v"(a), "v"(b));
    return r;
}

// kbu[w] = sum_h wd[w][h] * bu[h]  (bias-evolution constant for bu-elimination)
__global__ void kbu_kernel(const float* __restrict__ wd,
                           const float* __restrict__ bu,
                           float* __restrict__ kbu) {
    int c = threadIdx.x;
    if (c < WW) {
        float acc = 0.f;
        for (int h = 0; h < HH; ++h) acc = fmaf(wd[c * HH + h], bu[h], acc);
        kbu[c] = acc;
    }
}

__global__ __launch_bounds__(256, 4)
void proc_kernel(const float* __restrict__ x,
                 const float* __restrict__ program,
                 const float* __restrict__ wd,
                 const float* __restrict__ bd,
                 const float* __restrict__ wu,
                 const float* __restrict__ bu,
                 const float* __restrict__ kbu,
                 float* __restrict__ out)
{
    // only LDS left: read-only program table (4 KB)
    __shared__ __align__(16) float prog_lds[LL * WW];

    const int tid  = threadIdx.x;      // 0..255 (4 waves, each owns 16 rows)
    const int lane = tid & 63;
    const int wid  = tid >> 6;
    const int c    = lane & 15;        // batch-col within tile
    const int q    = lane >> 4;        // quad group
    const long row = (long)blockIdx.x * 64 + wid * 16 + c;

    // stage program (64x16 fp32): each thread copies one float4
    {
        const float4* ps = (const float4*)program;
        float4* pd = (float4*)prog_lds;
        pd[tid] = ps[tid];
    }

    // ---- preload wd A-frags: A[m=w=c][k=h=kc*32+q*8+j], K=128 in 4 chunks
    bf16x8 a_wd[4];
    #pragma unroll
    for (int kc = 0; kc < 4; ++kc) {
        const float* p = wd + c * HH + kc * 32 + q * 8;
        float4 f0 = *(const float4*)p;
        float4 f1 = *(const float4*)(p + 4);
        FragU u;
        u.u[0] = cvt_pk(f0.x, f0.y); u.u[1] = cvt_pk(f0.z, f0.w);
        u.u[2] = cvt_pk(f1.x, f1.y); u.u[3] = cvt_pk(f1.z, f1.w);
        a_wd[kc] = u.v;
    }

    // ---- preload wu A-frags: A[m=h=hc*16+c][k=w=q*8+j], zeros for k>=16 (q>=2)
    // (zeros in A mean the k>=16 slots of the up-proj B operand may hold junk)
    bf16x8 a_wu[8];
    #pragma unroll
    for (int hc = 0; hc < 8; ++hc) {
        FragU u;
        if (q < 2) {
            const float* p = wu + (hc * 16 + c) * WW + q * 8;
            float4 f0 = *(const float4*)p;
            float4 f1 = *(const float4*)(p + 4);
            u.u[0] = cvt_pk(f0.x, f0.y); u.u[1] = cvt_pk(f0.z, f0.w);
            u.u[2] = cvt_pk(f1.x, f1.y); u.u[3] = cvt_pk(f1.z, f1.w);
        } else {
            u.u[0] = 0; u.u[1] = 0; u.u[2] = 0; u.u[3] = 0;
        }
        a_wu[hc] = u.v;
    }

    // per-lane bias constants for this lane's w-slots (w = q*4+r)
    float4 bd4  = *(const float4*)(bd + q * 4);
    float4 kbu4 = *(const float4*)(kbu + q * 4);

    // ---- load X tile into C-layout accumulators: acc[hc][r] = X[row][hc*16+q*4+r]
    f32x4 acc[8];
    #pragma unroll
    for (int hc = 0; hc < 8; ++hc) {
        float4 f = *(const float4*)(x + row * HH + hc * 16 + q * 4);
        acc[hc][0] = f.x; acc[hc][1] = f.y; acc[hc][2] = f.z; acc[hc][3] = f.w;
    }

    __syncthreads();   // prog_lds ready — the only barrier in the kernel

    for (int l = 0; l < LL; ++l) {
        // 1. down-proj: build B-frags (B[k=h][n=c] = Y[c][h]) fully in-register.
        //    acc dwords a0,a1 (hc=2kc) / b0,b1 (hc=2kc+1) hold h = 32kc+4q+{0..3}
        //    (+16); frag dword t must hold h = 32kc+8q+2t.  P32 then P16 gives:
        //      P32(a0,b0) -> X=[a0q0,a0q1,b0q0,b0q1], Y=[a0q2,a0q3,b0q2,b0q3]
        //      P16(X,Y)   -> t0=[a0q0,a0q2,b0q0,b0q2], t2=[a0q1,a0q3,b0q1,b0q3]
        //    and (a1,b1) likewise gives t1,t3.
        f32x4 dreg = {0.f, 0.f, 0.f, 0.f};
        #pragma unroll
        for (int kc = 0; kc < 4; ++kc) {
            unsigned a0 = cvt_pk(acc[2*kc  ][0], acc[2*kc  ][1]);
            unsigned a1 = cvt_pk(acc[2*kc  ][2], acc[2*kc  ][3]);
            unsigned b0 = cvt_pk(acc[2*kc+1][0], acc[2*kc+1][1]);
            unsigned b1 = cvt_pk(acc[2*kc+1][2], acc[2*kc+1][3]);
            u32x2 sa = __builtin_amdgcn_permlane32_swap(a0, b0, false, false);
            u32x2 ta = __builtin_amdgcn_permlane16_swap(sa[0], sa[1], false, false);
            u32x2 sb = __builtin_amdgcn_permlane32_swap(a1, b1, false, false);
            u32x2 tb = __builtin_amdgcn_permlane16_swap(sb[0], sb[1], false, false);
            FragU f;
            f.u[0] = ta[0]; f.u[1] = tb[0]; f.u[2] = ta[1]; f.u[3] = tb[1];
            dreg = __builtin_amdgcn_mfma_f32_16x16x32_bf16(a_wd[kc], f.v, dreg, 0, 0, 0);
        }

        // 2. epilogue: reg = relu(d + bd + l*kbu) * inst[l]   (w = q*4+r)
        float4 instv = *(const float4*)(&prog_lds[l * WW + q * 4]);
        float lf = (float)l;
        float r0 = fmaxf(dreg[0] + fmaf(lf, kbu4.x, bd4.x), 0.f) * instv.x;
        float r1 = fmaxf(dreg[1] + fmaf(lf, kbu4.y, bd4.y), 0.f) * instv.y;
        float r2 = fmaxf(dreg[2] + fmaf(lf, kbu4.z, bd4.z), 0.f) * instv.z;
        float r3 = fmaxf(dreg[3] + fmaf(lf, kbu4.w, bd4.w), 0.f) * instv.w;

        // 3. up-proj B-frag in-register: lane needs reg[c][w=q*8+j] for k<16
        //    (k>=16 dwords are junk — multiplied by the zero half of a_wu).
        //      d0=pack(r0,r1) d1=pack(r2,r3) hold w = 4q+{0,1}/{2,3}
        //      P32(d0,d1) -> X=[d0q0,d0q1,d1q0,d1q1], Y=[d0q2,d0q3,d1q2,d1q3]
        //      P16(X,Y)   -> g0=[d0q0,d0q2,d1q0,d1q2], g2=[d0q1,d0q3,d1q1,d1q3]
        //      g1 = hi-half of g0 (P32 self-swap), g3 = hi-half of g2.
        unsigned d0 = cvt_pk(r0, r1);
        unsigned d1 = cvt_pk(r2, r3);
        u32x2 s1 = __builtin_amdgcn_permlane32_swap(d0, d1, false, false);
        u32x2 t1 = __builtin_amdgcn_permlane16_swap(s1[0], s1[1], false, false);
        u32x2 g1 = __builtin_amdgcn_permlane32_swap(t1[0], t1[0], false, false);
        u32x2 g3 = __builtin_amdgcn_permlane32_swap(t1[1], t1[1], false, false);
        FragU rf;
        rf.u[0] = t1[0]; rf.u[1] = g1[1]; rf.u[2] = t1[1]; rf.u[3] = g3[1];

        // 4. up-proj: Y[m][h] += reg[m][w] * wu[h][w], K=16 (padded to 32)
        #pragma unroll
        for (int hc = 0; hc < 8; ++hc) {
            acc[hc] = __builtin_amdgcn_mfma_f32_16x16x32_bf16(a_wu[hc], rf.v, acc[hc], 0, 0, 0);
        }
    }

    // ---- store out = Y + 64*bu
    #pragma unroll
    for (int hc = 0; hc < 8; ++hc) {
        float4 bv = *(const float4*)(bu + hc * 16 + q * 4);
        float4 o;
        o.x = acc[hc][0] + 64.f * bv.x;
        o.y = acc[hc][1] + 64.f * bv.y;
        o.z = acc[hc][2] + 64.f * bv.z;
        o.w = acc[hc][3] + 64.f * bv.w;
        *(float4*)(out + row * HH + hc * 16 + q * 4) = o;
    }
}

extern "C" void kernel_launch(void* const* d_in, const int* in_sizes, int n_in,
                              void* d_out, int out_size, void* d_ws, size_t ws_size,
                              hipStream_t stream) {
    const float* x  = (const float*)d_in[0];
    const float* pr = (const float*)d_in[1];
    const float* wd = (const float*)d_in[2];
    const float* bd = (const float*)d_in[3];
    const float* wu = (const float*)d_in[4];
    const float* bu = (const float*)d_in[5];
    float* out = (float*)d_out;
    float* kbu = (float*)d_ws;   // 16 floats of scratch

    kbu_kernel<<<1, 64, 0, stream>>>(wd, bu, kbu);
    proc_kernel<<<NB / 64, 256, 0, stream>>>(x, pr, wd, bd, wu, bu, kbu, out);
}

// Round 2
// 313.914 us; speedup vs baseline: 1.5280x; 1.2018x over previous
//
#include <hip/hip_runtime.h>

#define NB 262144
#define HH 128
#define WW 16
#define LL 64

typedef __attribute__((ext_vector_type(8))) short bf16x8;
typedef __attribute__((ext_vector_type(4))) float f32x4;

union FragU { bf16x8 v; unsigned int u[4]; };

// hardware RNE pack of two f32 -> 2x bf16 (lo = a, hi = b); bit-exact vs
// __float2bfloat16_rn for finite values
__device__ __forceinline__ unsigned int cvt_pk(float a, float b) {
    unsigned int r;
    asm("v_cvt_pk_bf16_f32 %0, %1, %2" : "=v"(r) : "v"(a), "v"(b));
    return r;
}

// kbu[w] = sum_h wd[w][h] * bu[h]  (bias-evolution constant for bu-elimination)
__global__ void kbu_kernel(const float* __restrict__ wd,
                           const float* __restrict__ bu,
                           float* __restrict__ kbu) {
    int c = threadIdx.x;
    if (c < WW) {
        float acc = 0.f;
        for (int h = 0; h < HH; ++h) acc = fmaf(wd[c * HH + h], bu[h], acc);
        kbu[c] = acc;
    }
}

__global__ __launch_bounds__(256, 4)
void proc_kernel(const float* __restrict__ x,
                 const float* __restrict__ program,
                 const float* __restrict__ wd,
                 const float* __restrict__ bd,
                 const float* __restrict__ wu,
                 const float* __restrict__ bu,
                 const float* __restrict__ kbu,
                 float* __restrict__ out)
{
    // only LDS: read-only program table (4 KB)
    __shared__ __align__(16) float prog_lds[LL * WW];

    const int tid  = threadIdx.x;      // 0..255 (4 waves, each owns 16 rows)
    const int lane = tid & 63;
    const int wid  = tid >> 6;
    const int c    = lane & 15;        // batch-col within tile
    const int q    = lane >> 4;        // quad group
    const long row = (long)blockIdx.x * 64 + wid * 16 + c;

    // stage program (64x16 fp32): each thread copies one float4
    {
        const float4* ps = (const float4*)program;
        float4* pd = (float4*)prog_lds;
        pd[tid] = ps[tid];
    }

    // ---- preload wd A-frags with PERMUTED k-assignment so the B operand can be
    // fed straight from the accumulators (no cross-lane shuffles anywhere):
    //   A-slot (q, j) of chunk kc  <->  physical h = kc*32 + (j>=4 ? 16 : 0) + q*4 + (j&3)
    // which is exactly where acc[2kc+(j>=4)][j&3] lives (acc[hc][r] = Y[.][hc*16+q*4+r]).
    bf16x8 a_wd[4];
    #pragma unroll
    for (int kc = 0; kc < 4; ++kc) {
        const float* p = wd + c * HH + kc * 32 + q * 4;
        float4 f0 = *(const float4*)p;          // h = kc*32      + q*4 + {0..3}
        float4 f1 = *(const float4*)(p + 16);   // h = kc*32 + 16 + q*4 + {0..3}
        FragU u;
        u.u[0] = cvt_pk(f0.x, f0.y); u.u[1] = cvt_pk(f0.z, f0.w);
        u.u[2] = cvt_pk(f1.x, f1.y); u.u[3] = cvt_pk(f1.z, f1.w);
        a_wd[kc] = u.v;
    }

    // ---- preload wu A-frags, k-assignment matched to the epilogue registers:
    //   A-slot (q, j<4) <-> w = q*4 + j   (pairs with rf = {pack(r0,r1),pack(r2,r3)})
    //   A-slot (q, j>=4) = 0              (pairs with finite junk in B)
    bf16x8 a_wu[8];
    #pragma unroll
    for (int hc = 0; hc < 8; ++hc) {
        const float* p = wu + (hc * 16 + c) * WW + q * 4;
        float4 f0 = *(const float4*)p;
        FragU u;
        u.u[0] = cvt_pk(f0.x, f0.y); u.u[1] = cvt_pk(f0.z, f0.w);
        u.u[2] = 0; u.u[3] = 0;
        a_wu[hc] = u.v;
    }

    // per-lane bias constants for this lane's w-slots (w = q*4+r)
    float4 bd4  = *(const float4*)(bd + q * 4);
    float4 kbu4 = *(const float4*)(kbu + q * 4);

    // ---- load X tile into C-layout accumulators: acc[hc][r] = X[row][hc*16+q*4+r]
    f32x4 acc[8];
    #pragma unroll
    for (int hc = 0; hc < 8; ++hc) {
        float4 f = *(const float4*)(x + row * HH + hc * 16 + q * 4);
        acc[hc][0] = f.x; acc[hc][1] = f.y; acc[hc][2] = f.z; acc[hc][3] = f.w;
    }

    __syncthreads();   // prog_lds ready — the only barrier in the kernel

    float lf = 0.f;
    for (int l = 0; l < LL; ++l) {
        float4 instv = *(const float4*)(&prog_lds[l * WW + q * 4]);

        // 1. down-proj: D[w][m] += wd[w][h] * Y[m][h], K=128.  B operand is the
        // packed accumulators directly (k-permutation folded into a_wd).
        f32x4 dreg = {0.f, 0.f, 0.f, 0.f};
        #pragma unroll
        for (int kc = 0; kc < 4; ++kc) {
            FragU b;
            b.u[0] = cvt_pk(acc[2*kc  ][0], acc[2*kc  ][1]);
            b.u[1] = cvt_pk(acc[2*kc  ][2], acc[2*kc  ][3]);
            b.u[2] = cvt_pk(acc[2*kc+1][0], acc[2*kc+1][1]);
            b.u[3] = cvt_pk(acc[2*kc+1][2], acc[2*kc+1][3]);
            dreg = __builtin_amdgcn_mfma_f32_16x16x32_bf16(a_wd[kc], b.v, dreg, 0, 0, 0);
        }

        // 2. epilogue: reg = relu(d + bd + l*kbu) * inst[l]   (w = q*4+r)
        float r0 = fmaxf(dreg[0] + fmaf(lf, kbu4.x, bd4.x), 0.f) * instv.x;
        float r1 = fmaxf(dreg[1] + fmaf(lf, kbu4.y, bd4.y), 0.f) * instv.y;
        float r2 = fmaxf(dreg[2] + fmaf(lf, kbu4.z, bd4.z), 0.f) * instv.z;
        float r3 = fmaxf(dreg[3] + fmaf(lf, kbu4.w, bd4.w), 0.f) * instv.w;

        // 3. up-proj B operand straight from the epilogue registers; upper half is
        // finite junk (copies) multiplied by the zero half of a_wu.
        FragU rf;
        rf.u[0] = cvt_pk(r0, r1);
        rf.u[1] = cvt_pk(r2, r3);
        rf.u[2] = rf.u[0];
        rf.u[3] = rf.u[1];

        // 4. up-proj: Y[m][h] += reg[m][w] * wu[h][w], K=16 (padded to 32)
        #pragma unroll
        for (int hc = 0; hc < 8; ++hc) {
            acc[hc] = __builtin_amdgcn_mfma_f32_16x16x32_bf16(a_wu[hc], rf.v, acc[hc], 0, 0, 0);
        }

        lf += 1.0f;
    }

    // ---- store out = Y + 64*bu
    #pragma unroll
    for (int hc = 0; hc < 8; ++hc) {
        float4 bv = *(const float4*)(bu + hc * 16 + q * 4);
        float4 o;
        o.x = acc[hc][0] + 64.f * bv.x;
        o.y = acc[hc][1] + 64.f * bv.y;
        o.z = acc[hc][2] + 64.f * bv.z;
        o.w = acc[hc][3] + 64.f * bv.w;
        *(float4*)(out + row * HH + hc * 16 + q * 4) = o;
    }
}

extern "C" void kernel_launch(void* const* d_in, const int* in_sizes, int n_in,
                              void* d_out, int out_size, void* d_ws, size_t ws_size,
                              hipStream_t stream) {
    const float* x  = (const float*)d_in[0];
    const float* pr = (const float*)d_in[1];
    const float* wd = (const float*)d_in[2];
    const float* bd = (const float*)d_in[3];
    const float* wu = (const float*)d_in[4];
    const float* bu = (const float*)d_in[5];
    float* out = (float*)d_out;
    float* kbu = (float*)d_ws;   // 16 floats of scratch

    kbu_kernel<<<1, 64, 0, stream>>>(wd, bu, kbu);
    proc_kernel<<<NB / 64, 256, 0, stream>>>(x, pr, wd, bd, wu, bu, kbu, out);
}